// Round 2
// baseline (1680.794 us; speedup 1.0000x reference)
//
#include <hip/hip_runtime.h>

typedef _Float16 f16;
typedef f16 f16x8 __attribute__((ext_vector_type(8)));
typedef float f32x4 __attribute__((ext_vector_type(4)));

#define NTOK 4096
#define EDIM 1024
#define KQKV 8192
#define SEQ  1024
#define HD   64

__device__ __forceinline__ float dot4(f32x4 a, f32x4 b) {
  return a[0]*b[0] + a[1]*b[1] + a[2]*b[2] + a[3]*b[3];
}

// async global->LDS, 16B per lane (global_load_lds_dwordx4)
__device__ __forceinline__ void gl16(const void* g, void* l) {
  __builtin_amdgcn_global_load_lds(
      (const __attribute__((address_space(1))) void*)g,
      (__attribute__((address_space(3))) void*)l, 16, 0, 0);
}

// ---------- fp32 -> fp16 hi/lo planar split (error ~2^-21 per value) ----------
__global__ void k_split(const float* __restrict__ in, f16* __restrict__ hi,
                        f16* __restrict__ lo, int n8) {
  int stride = gridDim.x * blockDim.x;
  for (int i = blockIdx.x * blockDim.x + threadIdx.x; i < n8; i += stride) {
    const float4* p = (const float4*)in + (size_t)i * 2;
    float4 a = p[0], b = p[1];
    float v[8] = {a.x, a.y, a.z, a.w, b.x, b.y, b.z, b.w};
    f16x8 h, l;
#pragma unroll
    for (int j = 0; j < 8; j++) {
      f16 hv = (f16)v[j];
      h[j] = hv;
      l[j] = (f16)(v[j] - (float)hv);
    }
    ((f16x8*)hi)[i] = h;
    ((f16x8*)lo)[i] = l;
  }
}

// ---------- WsumT[f][e] = sum_d Wout[e][f][d]  (transposing reduce) ----------
__global__ void k_wsumt(const float* __restrict__ wout, float* __restrict__ wsumT) {
  __shared__ float tile[32][65];
  int e0 = blockIdx.x * 32, f0 = blockIdx.y * 64;
  int t = threadIdx.x;
#pragma unroll
  for (int rep = 0; rep < 8; rep++) {
    int idx = rep * 256 + t;
    int el = idx >> 6, fl = idx & 63;
    const float* p = wout + ((size_t)(e0 + el) * 1024 + (f0 + fl)) * 8;
    float4 r0 = *(const float4*)p, r1 = *(const float4*)(p + 4);
    tile[el][fl] = r0.x + r0.y + r0.z + r0.w + r1.x + r1.y + r1.z + r1.w;
  }
  __syncthreads();
#pragma unroll
  for (int rep = 0; rep < 8; rep++) {
    int idx = rep * 256 + t;
    int fl = idx >> 5, el = idx & 31;
    wsumT[(size_t)(f0 + fl) * 1024 + (e0 + el)] = tile[el][fl];
  }
}

// ---------- QKV split-fp16 MFMA GEMM, m97-style LDS staging ----------
// A (x hi/lo): [4096][8192] planar fp16, k = e*8+d contiguous.
// B (W hi/lo): [e][f][d]; one e-row of a 128-col tile = contiguous 2KB.
// Block tile 128x128, BK=32 (4 e-rows), 4 waves (2x2), 64x64 per wave.
// LDS 32KB: Ah/Al [128 rows][4 chunks of 16B, XOR-swizzled], Bh/Bl [4][128][8].
__global__ __launch_bounds__(256, 2)
void k_gemm_qkv(const f16* __restrict__ xhi, const f16* __restrict__ xlo,
                const f16* __restrict__ wqh, const f16* __restrict__ wql,
                const f16* __restrict__ wkh, const f16* __restrict__ wkl,
                const f16* __restrict__ wvh, const f16* __restrict__ wvl,
                const float* __restrict__ qb, const float* __restrict__ kb,
                const float* __restrict__ vb,
                float* __restrict__ Q, float* __restrict__ K, float* __restrict__ V) {
  __shared__ __align__(16) f16 lAh[4096];   // 8KB: [row 0..127][chunk 0..3][8]
  __shared__ __align__(16) f16 lAl[4096];
  __shared__ __align__(16) f16 lBh[4096];   // 8KB: [e' 0..3][f 0..127][8]
  __shared__ __align__(16) f16 lBl[4096];

  int z = blockIdx.z;
  const f16* bh_ = z == 0 ? wqh : (z == 1 ? wkh : wvh);
  const f16* bl_ = z == 0 ? wql : (z == 1 ? wkl : wvl);
  const float* bias = z == 0 ? qb : (z == 1 ? kb : vb);
  float* out = z == 0 ? Q : (z == 1 ? K : V);

  int t = threadIdx.x;
  int wave = t >> 6, lane = t & 63;
  int lr = lane & 15, lk = lane >> 4;
  int wr = wave >> 1, wc = wave & 1;
  int rowblk = blockIdx.x * 128, colblk = blockIdx.y * 128;

  // ---- staging addresses ----
  // A: slot s (0..511): row=s>>2, chunk cs=s&3; stores global chunk cs^((row>>1)&3).
  //    thread t covers slots {t, t+256}; slot t+256 is row+64, same swizzle.
  {
  }
  int arow = t >> 2, acs = t & 3;
  int agc = acs ^ ((arow >> 1) & 3);
  const f16* pAh = xhi + (size_t)(rowblk + arow) * KQKV + (agc << 3);
  const f16* pAl = xlo + (size_t)(rowblk + arow) * KQKV + (agc << 3);
  // B: slot s: e'=s>>7, c=s&127; thread t covers {t, t+256} (e' and e'+2).
  const f16* pBh = bh_ + (size_t)(t >> 7) * 8192 + ((size_t)colblk + (t & 127)) * 8;
  const f16* pBl = bl_ + (size_t)(t >> 7) * 8192 + ((size_t)colblk + (t & 127)) * 8;

  f16* dAh0 = lAh + t * 8;            f16* dAh1 = lAh + (t + 256) * 8;
  f16* dAl0 = lAl + t * 8;            f16* dAl1 = lAl + (t + 256) * 8;
  f16* dBh0 = lBh + t * 8;            f16* dBh1 = lBh + (t + 256) * 8;
  f16* dBl0 = lBl + t * 8;            f16* dBl1 = lBl + (t + 256) * 8;

  // ---- fragment LDS indices (f16 units) ----
  // A frag m: row = wr*64+m*16+lr, chunk lk ^ ((lr>>1)&3)  (row>>1 ≡ lr>>1 mod 4)
  int aswz = (lk ^ ((lr >> 1) & 3)) << 3;
  int aidx[4];
#pragma unroll
  for (int m = 0; m < 4; m++) aidx[m] = (wr * 64 + m * 16 + lr) * 32 + aswz;
  int bidx[4];
#pragma unroll
  for (int n = 0; n < 4; n++) bidx[n] = (lk * 128 + wc * 64 + n * 16 + lr) << 3;

  f32x4 acc[4][4] = {};

  for (int kt = 0; kt < KQKV / 32; ++kt) {
    gl16(pAh, dAh0);  gl16(pAh + 64 * KQKV, dAh1);
    gl16(pAl, dAl0);  gl16(pAl + 64 * KQKV, dAl1);
    gl16(pBh, dBh0);  gl16(pBh + 2 * 8192, dBh1);
    gl16(pBl, dBl0);  gl16(pBl + 2 * 8192, dBl1);
    pAh += 32; pAl += 32; pBh += 4 * 8192; pBl += 4 * 8192;

    __syncthreads();   // drains vmcnt -> tile visible

    f16x8 ah[4], al[4], bh[4], bl[4];
#pragma unroll
    for (int m = 0; m < 4; m++) {
      ah[m] = *(const f16x8*)&lAh[aidx[m]];
      al[m] = *(const f16x8*)&lAl[aidx[m]];
    }
#pragma unroll
    for (int n = 0; n < 4; n++) {
      bh[n] = *(const f16x8*)&lBh[bidx[n]];
      bl[n] = *(const f16x8*)&lBl[bidx[n]];
    }
#pragma unroll
    for (int m = 0; m < 4; m++)
#pragma unroll
      for (int n = 0; n < 4; n++) {
        acc[m][n] = __builtin_amdgcn_mfma_f32_16x16x32_f16(ah[m], bh[n], acc[m][n], 0, 0, 0);
        acc[m][n] = __builtin_amdgcn_mfma_f32_16x16x32_f16(ah[m], bl[n], acc[m][n], 0, 0, 0);
        acc[m][n] = __builtin_amdgcn_mfma_f32_16x16x32_f16(al[m], bh[n], acc[m][n], 0, 0, 0);
      }

    __syncthreads();   // all reads done before next overwrite
  }

  int row0 = rowblk + wr * 64, col0 = colblk + wc * 64;
  float bv[4];
#pragma unroll
  for (int n = 0; n < 4; n++) bv[n] = bias[col0 + n * 16 + lr];
#pragma unroll
  for (int m = 0; m < 4; m++) {
    int r0 = row0 + m * 16 + lk * 4;
#pragma unroll
    for (int n = 0; n < 4; n++) {
      int c = col0 + n * 16 + lr;
      float* dst = out + (size_t)r0 * EDIM + c;
#pragma unroll
      for (int i = 0; i < 4; i++)
        dst[(size_t)i * EDIM] = acc[m][n][i] + bv[n];
    }
  }
}

// ---------- scores: S[bh][q][k] = scale * Q[q,:]·K[k,:]  (K-dim = 64) ----------
__global__ __launch_bounds__(256)
void k_scores(const float* __restrict__ Q, const float* __restrict__ K,
              float* __restrict__ attn) {
  __shared__ float Qt[64][68];
  __shared__ float Kt[64][68];
  int z = blockIdx.z;            // b*16 + h
  int b = z >> 4, h = z & 15;
  int q0 = blockIdx.x * 64, k0 = blockIdx.y * 64;
  int t = threadIdx.x;
  size_t qbase = ((size_t)(b * SEQ + q0)) * EDIM + h * HD;
  size_t kbase = ((size_t)(b * SEQ + k0)) * EDIM + h * HD;
#pragma unroll
  for (int rep = 0; rep < 4; rep++) {
    int idx = rep * 256 + t;
    int r = idx >> 4, c4 = (idx & 15) * 4;
    *(f32x4*)&Qt[r][c4] = *(const f32x4*)(Q + qbase + (size_t)r * EDIM + c4);
    *(f32x4*)&Kt[r][c4] = *(const f32x4*)(K + kbase + (size_t)r * EDIM + c4);
  }
  __syncthreads();
  int tq = t >> 4, tk = t & 15;
  float acc[4][4] = {};
  for (int c0 = 0; c0 < 64; c0 += 4) {
    f32x4 a4[4], b4[4];
#pragma unroll
    for (int i = 0; i < 4; i++) a4[i] = *(const f32x4*)&Qt[tq + 16 * i][c0];
#pragma unroll
    for (int j = 0; j < 4; j++) b4[j] = *(const f32x4*)&Kt[tk + 16 * j][c0];
#pragma unroll
    for (int i = 0; i < 4; i++)
#pragma unroll
      for (int j = 0; j < 4; j++)
        acc[i][j] += dot4(a4[i], b4[j]);
  }
  const float scale = 0.125f;
  float* dst = attn + ((size_t)z * SEQ + q0) * SEQ + k0;
#pragma unroll
  for (int i = 0; i < 4; i++)
#pragma unroll
    for (int j = 0; j < 4; j++)
      dst[(size_t)(tq + 16 * i) * SEQ + tk + 16 * j] = acc[i][j] * scale;
}

// ---------- softmax over rows of attn (in place), one block per row ----------
__global__ __launch_bounds__(256)
void k_softmax(float* __restrict__ attn) {
  __shared__ float red[8];
  size_t row = blockIdx.x;
  float* p = attn + row * 1024;
  int t = threadIdx.x;
  float4 v = *(float4*)(p + t * 4);
  float m = fmaxf(fmaxf(v.x, v.y), fmaxf(v.z, v.w));
#pragma unroll
  for (int off = 1; off < 64; off <<= 1) m = fmaxf(m, __shfl_xor(m, off));
  int wv = t >> 6;
  if ((t & 63) == 0) red[wv] = m;
  __syncthreads();
  m = fmaxf(fmaxf(red[0], red[1]), fmaxf(red[2], red[3]));
  float4 e;
  e.x = __expf(v.x - m); e.y = __expf(v.y - m);
  e.z = __expf(v.z - m); e.w = __expf(v.w - m);
  float s = e.x + e.y + e.z + e.w;
#pragma unroll
  for (int off = 1; off < 64; off <<= 1) s += __shfl_xor(s, off);
  if ((t & 63) == 0) red[4 + wv] = s;
  __syncthreads();
  s = red[4] + red[5] + red[6] + red[7];
  float inv = 1.0f / s;
  v.x = e.x * inv; v.y = e.y * inv; v.z = e.z * inv; v.w = e.w * inv;
  *(float4*)(p + t * 4) = v;
}

// ---------- PV: aout[b,s,h,hd] = sum_k attn[bh][s][k] * V[b,k,h,hd] ----------
__global__ __launch_bounds__(256)
void k_pv(const float* __restrict__ attn, const float* __restrict__ V,
          float* __restrict__ aout) {
  __shared__ float Wt[64][68];
  __shared__ float VtT[64][68];   // transposed: VtT[hd][k]
  int z = blockIdx.y;
  int b = z >> 4, h = z & 15;
  int s0 = blockIdx.x * 64;
  int t = threadIdx.x;
  int tq = t >> 4, th = t & 15;
  float acc[4][4] = {};
  for (int k0 = 0; k0 < SEQ; k0 += 64) {
    __syncthreads();
#pragma unroll
    for (int rep = 0; rep < 4; rep++) {
      int idx = rep * 256 + t;
      int r = idx >> 4, c4 = (idx & 15) * 4;
      *(f32x4*)&Wt[r][c4] =
          *(const f32x4*)(attn + ((size_t)z * SEQ + s0 + r) * SEQ + k0 + c4);
      f32x4 vv = *(const f32x4*)(V + ((size_t)(b * SEQ + k0 + r)) * EDIM + h * HD + c4);
#pragma unroll
      for (int c = 0; c < 4; c++) VtT[c4 + c][r] = vv[c];
    }
    __syncthreads();
    for (int c0 = 0; c0 < 64; c0 += 4) {
      f32x4 a4[4], b4[4];
#pragma unroll
      for (int i = 0; i < 4; i++) a4[i] = *(const f32x4*)&Wt[tq + 16 * i][c0];
#pragma unroll
      for (int j = 0; j < 4; j++) b4[j] = *(const f32x4*)&VtT[th + 16 * j][c0];
#pragma unroll
      for (int i = 0; i < 4; i++)
#pragma unroll
        for (int j = 0; j < 4; j++)
          acc[i][j] += dot4(a4[i], b4[j]);
    }
  }
#pragma unroll
  for (int i = 0; i < 4; i++)
#pragma unroll
    for (int j = 0; j < 4; j++)
      aout[((size_t)(b * SEQ + s0 + tq + 16 * i)) * EDIM + h * HD + th + 16 * j] =
          acc[i][j];
}

// ---------- out projection: out[n][f] = sum_e aout[n][e]*WsumT[f][e] + bias[f] ----------
__global__ __launch_bounds__(256)
void k_outproj(const float* __restrict__ A, const float* __restrict__ BT,
               const float* __restrict__ bias, float* __restrict__ outp) {
  __shared__ float At[64][68];
  __shared__ float Bt[64][68];
  int n0 = blockIdx.x * 64, f0 = blockIdx.y * 64;
  int t = threadIdx.x;
  int tn = t >> 4, tf = t & 15;
  float acc[4][4] = {};
  for (int e0 = 0; e0 < EDIM; e0 += 64) {
    __syncthreads();
#pragma unroll
    for (int rep = 0; rep < 4; rep++) {
      int idx = rep * 256 + t;
      int r = idx >> 4, c4 = (idx & 15) * 4;
      *(f32x4*)&At[r][c4] = *(const f32x4*)(A + (size_t)(n0 + r) * EDIM + e0 + c4);
      *(f32x4*)&Bt[r][c4] = *(const f32x4*)(BT + (size_t)(f0 + r) * EDIM + e0 + c4);
    }
    __syncthreads();
    for (int c0 = 0; c0 < 64; c0 += 4) {
      f32x4 a4[4], b4[4];
#pragma unroll
      for (int i = 0; i < 4; i++) a4[i] = *(const f32x4*)&At[tn + 16 * i][c0];
#pragma unroll
      for (int j = 0; j < 4; j++) b4[j] = *(const f32x4*)&Bt[tf + 16 * j][c0];
#pragma unroll
      for (int i = 0; i < 4; i++)
#pragma unroll
        for (int j = 0; j < 4; j++)
          acc[i][j] += dot4(a4[i], b4[j]);
    }
  }
#pragma unroll
  for (int i = 0; i < 4; i++)
#pragma unroll
    for (int j = 0; j < 4; j++)
      outp[(size_t)(n0 + tn + 16 * i) * EDIM + f0 + tf + 16 * j] =
          acc[i][j] + bias[f0 + tf + 16 * j];
}

extern "C" void kernel_launch(void* const* d_in, const int* in_sizes, int n_in,
                              void* d_out, int out_size, void* d_ws, size_t ws_size,
                              hipStream_t stream) {
  const float* x  = (const float*)d_in[0];
  const float* wq = (const float*)d_in[1];
  const float* wk = (const float*)d_in[2];
  const float* wv = (const float*)d_in[3];
  const float* wo = (const float*)d_in[4];
  const float* qb = (const float*)d_in[5];
  const float* kb = (const float*)d_in[6];
  const float* vb = (const float*)d_in[7];
  const float* ob = (const float*)d_in[8];

  float* outp = (float*)d_out;
  float* attn = outp + (size_t)4 * 1024 * 1024;   // [64][1024][1024] fp32

  // workspace layout (306.2 MB total)
  char* w = (char*)d_ws;
  f16* xhi = (f16*)w;  w += (size_t)33554432 * 2;
  f16* xlo = (f16*)w;  w += (size_t)33554432 * 2;
  f16* wqh = (f16*)w;  w += (size_t)8388608 * 2;
  f16* wql = (f16*)w;  w += (size_t)8388608 * 2;
  f16* wkh = (f16*)w;  w += (size_t)8388608 * 2;
  f16* wkl = (f16*)w;  w += (size_t)8388608 * 2;
  f16* wvh = (f16*)w;  w += (size_t)8388608 * 2;
  f16* wvl = (f16*)w;  w += (size_t)8388608 * 2;
  float* Q    = (float*)w; w += (size_t)4194304 * 4;
  float* K    = (float*)w; w += (size_t)4194304 * 4;
  float* V    = (float*)w; w += (size_t)4194304 * 4;
  float* aout = (float*)w; w += (size_t)4194304 * 4;
  float* wsumT = (float*)w; w += (size_t)1048576 * 4;

  // 1. hi/lo splits
  k_split<<<8192, 256, 0, stream>>>(x, xhi, xlo, 4194304);
  k_split<<<4096, 256, 0, stream>>>(wq, wqh, wql, 1048576);
  k_split<<<4096, 256, 0, stream>>>(wk, wkh, wkl, 1048576);
  k_split<<<4096, 256, 0, stream>>>(wv, wvh, wvl, 1048576);
  // 2. transposed d-reduced output weight
  k_wsumt<<<dim3(32, 16), 256, 0, stream>>>(wo, wsumT);
  // 3. QKV projections (split-fp16 MFMA, LDS-staged)
  k_gemm_qkv<<<dim3(32, 8, 3), 256, 0, stream>>>(xhi, xlo, wqh, wql, wkh, wkl,
                                                 wvh, wvl, qb, kb, vb, Q, K, V);
  // 4. raw scores -> attn region of d_out
  k_scores<<<dim3(16, 16, 64), 256, 0, stream>>>(Q, K, attn);
  // 5. softmax in place
  k_softmax<<<65536, 256, 0, stream>>>(attn);
  // 6. PV
  k_pv<<<dim3(16, 64), 256, 0, stream>>>(attn, V, aout);
  // 7. output projection + bias
  k_outproj<<<dim3(64, 16), 256, 0, stream>>>(aout, wsumT, ob, outp);
}

// Round 3
// 1444.962 us; speedup vs baseline: 1.1632x; 1.1632x over previous
//
#include <hip/hip_runtime.h>

typedef _Float16 f16;
typedef f16 f16x8 __attribute__((ext_vector_type(8)));
typedef float f32x4 __attribute__((ext_vector_type(4)));

#define EDIM 1024
#define KQKV 8192
#define SEQ  1024
#define HD   64

// async global->LDS, 16B per lane (global_load_lds_dwordx4)
__device__ __forceinline__ void gl16(const void* g, void* l) {
  __builtin_amdgcn_global_load_lds(
      (const __attribute__((address_space(1))) void*)g,
      (__attribute__((address_space(3))) void*)l, 16, 0, 0);
}

// ---------- fp32 -> fp16 hi/lo planar split ----------
__global__ void k_split(const float* __restrict__ in, f16* __restrict__ hi,
                        f16* __restrict__ lo, int n8) {
  int stride = gridDim.x * blockDim.x;
  for (int i = blockIdx.x * blockDim.x + threadIdx.x; i < n8; i += stride) {
    const float4* p = (const float4*)in + (size_t)i * 2;
    float4 a = p[0], b = p[1];
    float v[8] = {a.x, a.y, a.z, a.w, b.x, b.y, b.z, b.w};
    f16x8 h, l;
#pragma unroll
    for (int j = 0; j < 8; j++) {
      f16 hv = (f16)v[j];
      h[j] = hv;
      l[j] = (f16)(v[j] - (float)hv);
    }
    ((f16x8*)hi)[i] = h;
    ((f16x8*)lo)[i] = l;
  }
}

// ---------- WsumT[f][e] = sum_d Wout[e][f][d], emitted as f16 hi/lo ----------
__global__ void k_wsumt(const float* __restrict__ wout, f16* __restrict__ wth,
                        f16* __restrict__ wtl) {
  __shared__ float tile[32][65];
  int e0 = blockIdx.x * 32, f0 = blockIdx.y * 64;
  int t = threadIdx.x;
#pragma unroll
  for (int rep = 0; rep < 8; rep++) {
    int idx = rep * 256 + t;
    int el = idx >> 6, fl = idx & 63;
    const float* p = wout + ((size_t)(e0 + el) * 1024 + (f0 + fl)) * 8;
    float4 r0 = *(const float4*)p, r1 = *(const float4*)(p + 4);
    tile[el][fl] = r0.x + r0.y + r0.z + r0.w + r1.x + r1.y + r1.z + r1.w;
  }
  __syncthreads();
#pragma unroll
  for (int rep = 0; rep < 8; rep++) {
    int idx = rep * 256 + t;
    int fl = idx >> 5, el = idx & 31;
    float v = tile[el][fl];
    f16 h = (f16)v;
    size_t o = (size_t)(f0 + fl) * 1024 + e0 + el;
    wth[o] = h;
    wtl[o] = (f16)(v - (float)h);
  }
}

// ---------- QKV split-fp16 MFMA GEMM, m97-style LDS staging ----------
// Grid (colblk=8, z=3, rowblk=32): row-block slowest => 24 consecutive blocks
// share one 4MB A-panel; L3 holds panel + all B => A streams HBM once.
__global__ __launch_bounds__(256, 2)
void k_gemm_qkv(const f16* __restrict__ xhi, const f16* __restrict__ xlo,
                const f16* __restrict__ wqh, const f16* __restrict__ wql,
                const f16* __restrict__ wkh, const f16* __restrict__ wkl,
                const f16* __restrict__ wvh, const f16* __restrict__ wvl,
                const float* __restrict__ qb, const float* __restrict__ kb,
                const float* __restrict__ vb,
                float* __restrict__ Q, float* __restrict__ K, float* __restrict__ V) {
  __shared__ __align__(16) f16 lAh[4096];
  __shared__ __align__(16) f16 lAl[4096];
  __shared__ __align__(16) f16 lBh[4096];
  __shared__ __align__(16) f16 lBl[4096];

  int z = blockIdx.y;
  const f16* bh_ = z == 0 ? wqh : (z == 1 ? wkh : wvh);
  const f16* bl_ = z == 0 ? wql : (z == 1 ? wkl : wvl);
  const float* bias = z == 0 ? qb : (z == 1 ? kb : vb);
  float* out = z == 0 ? Q : (z == 1 ? K : V);

  int t = threadIdx.x;
  int wave = t >> 6, lane = t & 63;
  int lr = lane & 15, lk = lane >> 4;
  int wr = wave >> 1, wc = wave & 1;
  int rowblk = blockIdx.z * 128, colblk = blockIdx.x * 128;

  int arow = t >> 2, acs = t & 3;
  int agc = acs ^ ((arow >> 1) & 3);
  const f16* pAh = xhi + (size_t)(rowblk + arow) * KQKV + (agc << 3);
  const f16* pAl = xlo + (size_t)(rowblk + arow) * KQKV + (agc << 3);
  const f16* pBh = bh_ + (size_t)(t >> 7) * 8192 + ((size_t)colblk + (t & 127)) * 8;
  const f16* pBl = bl_ + (size_t)(t >> 7) * 8192 + ((size_t)colblk + (t & 127)) * 8;

  f16* dAh0 = lAh + t * 8;  f16* dAh1 = lAh + (t + 256) * 8;
  f16* dAl0 = lAl + t * 8;  f16* dAl1 = lAl + (t + 256) * 8;
  f16* dBh0 = lBh + t * 8;  f16* dBh1 = lBh + (t + 256) * 8;
  f16* dBl0 = lBl + t * 8;  f16* dBl1 = lBl + (t + 256) * 8;

  int aswz = (lk ^ ((lr >> 1) & 3)) << 3;
  int aidx[4];
#pragma unroll
  for (int m = 0; m < 4; m++) aidx[m] = (wr * 64 + m * 16 + lr) * 32 + aswz;
  int bidx[4];
#pragma unroll
  for (int n = 0; n < 4; n++) bidx[n] = (lk * 128 + wc * 64 + n * 16 + lr) << 3;

  f32x4 acc[4][4] = {};

  for (int kt = 0; kt < KQKV / 32; ++kt) {
    gl16(pAh, dAh0);  gl16(pAh + 64 * KQKV, dAh1);
    gl16(pAl, dAl0);  gl16(pAl + 64 * KQKV, dAl1);
    gl16(pBh, dBh0);  gl16(pBh + 2 * 8192, dBh1);
    gl16(pBl, dBl0);  gl16(pBl + 2 * 8192, dBl1);
    pAh += 32; pAl += 32; pBh += 4 * 8192; pBl += 4 * 8192;

    __syncthreads();

    f16x8 ah[4], al[4], bh[4], bl[4];
#pragma unroll
    for (int m = 0; m < 4; m++) {
      ah[m] = *(const f16x8*)&lAh[aidx[m]];
      al[m] = *(const f16x8*)&lAl[aidx[m]];
    }
#pragma unroll
    for (int n = 0; n < 4; n++) {
      bh[n] = *(const f16x8*)&lBh[bidx[n]];
      bl[n] = *(const f16x8*)&lBl[bidx[n]];
    }
#pragma unroll
    for (int m = 0; m < 4; m++)
#pragma unroll
      for (int n = 0; n < 4; n++) {
        acc[m][n] = __builtin_amdgcn_mfma_f32_16x16x32_f16(ah[m], bh[n], acc[m][n], 0, 0, 0);
        acc[m][n] = __builtin_amdgcn_mfma_f32_16x16x32_f16(ah[m], bl[n], acc[m][n], 0, 0, 0);
        acc[m][n] = __builtin_amdgcn_mfma_f32_16x16x32_f16(al[m], bh[n], acc[m][n], 0, 0, 0);
      }

    __syncthreads();
  }

  int row0 = rowblk + wr * 64, col0 = colblk + wc * 64;
  float bv[4];
#pragma unroll
  for (int n = 0; n < 4; n++) bv[n] = bias[col0 + n * 16 + lr];
#pragma unroll
  for (int m = 0; m < 4; m++) {
    int r0 = row0 + m * 16 + lk * 4;
#pragma unroll
    for (int n = 0; n < 4; n++) {
      int c = col0 + n * 16 + lr;
      float* dst = out + (size_t)r0 * EDIM + c;
#pragma unroll
      for (int i = 0; i < 4; i++)
        dst[(size_t)i * EDIM] = acc[m][n][i] + bv[n];
    }
  }
}

// ---------- staging helpers for fused attention ----------
// 64x64 fp32 tile -> split f16 hi/lo in LDS, [row][8 chunks of 8], chunk ^= row&7
__device__ __forceinline__ void stage_tile64(const float* __restrict__ src,
                                             f16* __restrict__ dh, f16* __restrict__ dl,
                                             int sr, int sc4) {
  const float* p = src + (size_t)sr * EDIM + sc4;
  float4 v0 = *(const float4*)p;
  float4 v1 = *(const float4*)(p + 4);
  float4 v2 = *(const float4*)(p + 8);
  float4 v3 = *(const float4*)(p + 12);
  float vv[16] = {v0.x, v0.y, v0.z, v0.w, v1.x, v1.y, v1.z, v1.w,
                  v2.x, v2.y, v2.z, v2.w, v3.x, v3.y, v3.z, v3.w};
  f16x8 ha, la, hb, lb;
#pragma unroll
  for (int j = 0; j < 8; j++) {
    f16 x = (f16)vv[j];
    ha[j] = x; la[j] = (f16)(vv[j] - (float)x);
    f16 y = (f16)vv[8 + j];
    hb[j] = y; lb[j] = (f16)(vv[8 + j] - (float)y);
  }
  int c0 = sc4 >> 3;
  int ca = ((c0 ^ (sr & 7)) << 3), cb = (((c0 + 1) ^ (sr & 7)) << 3);
  *(f16x8*)&dh[sr * 64 + ca] = ha;
  *(f16x8*)&dl[sr * 64 + ca] = la;
  *(f16x8*)&dh[sr * 64 + cb] = hb;
  *(f16x8*)&dl[sr * 64 + cb] = lb;
}

// V tile transposed into [hd][64 keys] (key-contiguous for PV B-operand)
__device__ __forceinline__ void stage_vt(const float* __restrict__ src,
                                         f16* __restrict__ dh, f16* __restrict__ dl,
                                         int sr, int sc4) {
  const float* p = src + (size_t)sr * EDIM + sc4;
  float4 v0 = *(const float4*)p;
  float4 v1 = *(const float4*)(p + 4);
  float4 v2 = *(const float4*)(p + 8);
  float4 v3 = *(const float4*)(p + 12);
  float vv[16] = {v0.x, v0.y, v0.z, v0.w, v1.x, v1.y, v1.z, v1.w,
                  v2.x, v2.y, v2.z, v2.w, v3.x, v3.y, v3.z, v3.w};
#pragma unroll
  for (int j = 0; j < 16; j++) {
    int hd = sc4 + j;
    f16 x = (f16)vv[j];
    int off = hd * 64 + (((sr >> 3) ^ (hd & 7)) << 3) + (sr & 7);
    dh[off] = x;
    dl[off] = (f16)(vv[j] - (float)x);
  }
}

// ---------- fused attention: scores + softmax + P-write + PV ----------
// Block: one (b,h), 64 q-rows; 4 waves, each owns a 16-wide key/hd strip.
// Pass 1: running row max m, denom l (scores recomputed, never stored).
// Pass 2: recompute scores, write P = exp(s*scale - m)/l (fp32, output), PV MFMA.
__global__ __launch_bounds__(256)
void k_attn(const float* __restrict__ Qm, const float* __restrict__ Km,
            const float* __restrict__ Vm, float* __restrict__ attn,
            f16* __restrict__ aoh, f16* __restrict__ aol) {
  __shared__ __align__(16) f16 lKh[4096], lKl[4096];
  __shared__ __align__(16) f16 lVh[4096], lVl[4096];
  __shared__ __align__(16) f16 lP[4096];
  __shared__ float sred[4][64], ssum[4][64];
  __shared__ float m_run[64], l_run[64], linv[64];

  int z = blockIdx.y;
  int b = z >> 4, h = z & 15;
  int q0 = blockIdx.x * 64;
  int t = threadIdx.x;
  int w = t >> 6, lane = t & 63, lr = lane & 15, lk = lane >> 4;

  size_t qoff = ((size_t)b * SEQ + q0) * EDIM + h * HD;
  size_t koff = ((size_t)b * SEQ) * EDIM + h * HD;
  size_t abase = ((size_t)z * SEQ + q0) * SEQ;

  int sr = t >> 2, sc4 = (t & 3) * 16;

  // stage Q (borrow lKh/lKl), pull A-frags to registers
  stage_tile64(Qm + qoff, lKh, lKl, sr, sc4);
  __syncthreads();
  f16x8 qh[4][2], ql[4][2];
#pragma unroll
  for (int m = 0; m < 4; m++)
#pragma unroll
    for (int kk = 0; kk < 2; kk++) {
      int r = m * 16 + lr;
      int ch = (((kk * 4 + lk) ^ (r & 7)) << 3);
      qh[m][kk] = *(const f16x8*)&lKh[r * 64 + ch];
      ql[m][kk] = *(const f16x8*)&lKl[r * 64 + ch];
    }
  if (t < 64) { m_run[t] = -1e30f; l_run[t] = 0.f; }
  __syncthreads();

  // ================= PASS 1: m and l =================
  for (int kt = 0; kt < 16; kt++) {
    stage_tile64(Km + koff + (size_t)(kt * 64) * EDIM, lKh, lKl, sr, sc4);
    __syncthreads();

    f16x8 kbh[2], kbl[2];
#pragma unroll
    for (int kk = 0; kk < 2; kk++) {
      int r = w * 16 + lr;
      int ch = (((kk * 4 + lk) ^ (r & 7)) << 3);
      kbh[kk] = *(const f16x8*)&lKh[r * 64 + ch];
      kbl[kk] = *(const f16x8*)&lKl[r * 64 + ch];
    }
    f32x4 acc[4] = {};
#pragma unroll
    for (int m = 0; m < 4; m++)
#pragma unroll
      for (int kk = 0; kk < 2; kk++) {
        acc[m] = __builtin_amdgcn_mfma_f32_16x16x32_f16(qh[m][kk], kbh[kk], acc[m], 0, 0, 0);
        acc[m] = __builtin_amdgcn_mfma_f32_16x16x32_f16(qh[m][kk], kbl[kk], acc[m], 0, 0, 0);
        acc[m] = __builtin_amdgcn_mfma_f32_16x16x32_f16(ql[m][kk], kbh[kk], acc[m], 0, 0, 0);
      }

    float sv[4][4], rm[4][4];
#pragma unroll
    for (int m = 0; m < 4; m++)
#pragma unroll
      for (int i = 0; i < 4; i++) { sv[m][i] = acc[m][i] * 0.125f; rm[m][i] = sv[m][i]; }
#pragma unroll
    for (int off = 1; off < 16; off <<= 1)
#pragma unroll
      for (int m = 0; m < 4; m++)
#pragma unroll
        for (int i = 0; i < 4; i++)
          rm[m][i] = fmaxf(rm[m][i], __shfl_xor(rm[m][i], off));
    if (lr == 0) {
#pragma unroll
      for (int m = 0; m < 4; m++)
#pragma unroll
        for (int i = 0; i < 4; i++) sred[w][m * 16 + lk * 4 + i] = rm[m][i];
    }
    __syncthreads();
    if (t < 64) {
      float tm = fmaxf(fmaxf(sred[0][t], sred[1][t]), fmaxf(sred[2][t], sred[3][t]));
      float mn = fmaxf(m_run[t], tm);
      sred[0][t] = __expf(m_run[t] - mn);   // rescale factor for l
      m_run[t] = mn;
    }
    __syncthreads();
#pragma unroll
    for (int m = 0; m < 4; m++)
#pragma unroll
      for (int i = 0; i < 4; i++)
        sv[m][i] = __expf(sv[m][i] - m_run[m * 16 + lk * 4 + i]);
#pragma unroll
    for (int off = 1; off < 16; off <<= 1)
#pragma unroll
      for (int m = 0; m < 4; m++)
#pragma unroll
        for (int i = 0; i < 4; i++)
          sv[m][i] += __shfl_xor(sv[m][i], off);
    if (lr == 0) {
#pragma unroll
      for (int m = 0; m < 4; m++)
#pragma unroll
        for (int i = 0; i < 4; i++) ssum[w][m * 16 + lk * 4 + i] = sv[m][i];
    }
    __syncthreads();
    if (t < 64)
      l_run[t] = l_run[t] * sred[0][t] +
                 (ssum[0][t] + ssum[1][t] + ssum[2][t] + ssum[3][t]);
    __syncthreads();
  }
  if (t < 64) linv[t] = 1.0f / l_run[t];
  __syncthreads();

  // ================= PASS 2: P write + PV =================
  f32x4 acc_o[4] = {};
  for (int kt = 0; kt < 16; kt++) {
    stage_tile64(Km + koff + (size_t)(kt * 64) * EDIM, lKh, lKl, sr, sc4);
    stage_vt(Vm + koff + (size_t)(kt * 64) * EDIM, lVh, lVl, sr, sc4);
    __syncthreads();

    f16x8 kbh[2], kbl[2];
#pragma unroll
    for (int kk = 0; kk < 2; kk++) {
      int r = w * 16 + lr;
      int ch = (((kk * 4 + lk) ^ (r & 7)) << 3);
      kbh[kk] = *(const f16x8*)&lKh[r * 64 + ch];
      kbl[kk] = *(const f16x8*)&lKl[r * 64 + ch];
    }
    f32x4 acc[4] = {};
#pragma unroll
    for (int m = 0; m < 4; m++)
#pragma unroll
      for (int kk = 0; kk < 2; kk++) {
        acc[m] = __builtin_amdgcn_mfma_f32_16x16x32_f16(qh[m][kk], kbh[kk], acc[m], 0, 0, 0);
        acc[m] = __builtin_amdgcn_mfma_f32_16x16x32_f16(qh[m][kk], kbl[kk], acc[m], 0, 0, 0);
        acc[m] = __builtin_amdgcn_mfma_f32_16x16x32_f16(ql[m][kk], kbh[kk], acc[m], 0, 0, 0);
      }

#pragma unroll
    for (int m = 0; m < 4; m++)
#pragma unroll
      for (int i = 0; i < 4; i++) {
        int row = m * 16 + lk * 4 + i;
        float pr = __expf(acc[m][i] * 0.125f - m_run[row]) * linv[row];
        attn[abase + (size_t)row * SEQ + kt * 64 + w * 16 + lr] = pr;
        int key = w * 16 + lr;
        lP[row * 64 + (((key >> 3) ^ (row & 7)) << 3) + (key & 7)] = (f16)pr;
      }
    __syncthreads();

#pragma unroll
    for (int kk = 0; kk < 2; kk++) {
      int rv = w * 16 + lr;
      int chv = (((kk * 4 + lk) ^ (rv & 7)) << 3);
      f16x8 vbh = *(const f16x8*)&lVh[rv * 64 + chv];
      f16x8 vbl = *(const f16x8*)&lVl[rv * 64 + chv];
#pragma unroll
      for (int m = 0; m < 4; m++) {
        int rp = m * 16 + lr;
        int chp = (((kk * 4 + lk) ^ (rp & 7)) << 3);
        f16x8 pa = *(const f16x8*)&lP[rp * 64 + chp];
        acc_o[m] = __builtin_amdgcn_mfma_f32_16x16x32_f16(pa, vbh, acc_o[m], 0, 0, 0);
        acc_o[m] = __builtin_amdgcn_mfma_f32_16x16x32_f16(pa, vbl, acc_o[m], 0, 0, 0);
      }
    }
    __syncthreads();
  }

  // epilogue: aout as split f16 hi/lo (feeds k_outproj)
  size_t obase = ((size_t)b * SEQ + q0) * EDIM + h * HD + w * 16 + lr;
#pragma unroll
  for (int m = 0; m < 4; m++)
#pragma unroll
    for (int i = 0; i < 4; i++) {
      int row = m * 16 + lk * 4 + i;
      float v = acc_o[m][i];
      f16 hh = (f16)v;
      aoh[obase + (size_t)row * EDIM] = hh;
      aol[obase + (size_t)row * EDIM] = (f16)(v - (float)hh);
    }
}

// ---------- out projection MFMA: out[n][f] = aout[n][:]·wsumT[f][:] + bias ----------
__global__ __launch_bounds__(256, 2)
void k_outproj(const f16* __restrict__ aoh, const f16* __restrict__ aol,
               const f16* __restrict__ wth, const f16* __restrict__ wtl,
               const float* __restrict__ bias, float* __restrict__ outp) {
  __shared__ __align__(16) f16 lAh[4096], lAl[4096], lBh[4096], lBl[4096];

  int t = threadIdx.x;
  int wave = t >> 6, lane = t & 63;
  int lr = lane & 15, lk = lane >> 4;
  int wr = wave >> 1, wc = wave & 1;
  int rowblk = blockIdx.y * 128, colblk = blockIdx.x * 128;

  int arow = t >> 2, acs = t & 3;
  int agc = acs ^ ((arow >> 1) & 3);
  const f16* pAh = aoh + (size_t)(rowblk + arow) * EDIM + (agc << 3);
  const f16* pAl = aol + (size_t)(rowblk + arow) * EDIM + (agc << 3);
  const f16* pBh = wth + (size_t)(colblk + arow) * EDIM + (agc << 3);
  const f16* pBl = wtl + (size_t)(colblk + arow) * EDIM + (agc << 3);

  f16* dAh0 = lAh + t * 8;  f16* dAh1 = lAh + (t + 256) * 8;
  f16* dAl0 = lAl + t * 8;  f16* dAl1 = lAl + (t + 256) * 8;
  f16* dBh0 = lBh + t * 8;  f16* dBh1 = lBh + (t + 256) * 8;
  f16* dBl0 = lBl + t * 8;  f16* dBl1 = lBl + (t + 256) * 8;

  int aswz = (lk ^ ((lr >> 1) & 3)) << 3;
  int aidx[4], bidx[4];
#pragma unroll
  for (int m = 0; m < 4; m++) aidx[m] = (wr * 64 + m * 16 + lr) * 32 + aswz;
#pragma unroll
  for (int n = 0; n < 4; n++) bidx[n] = (wc * 64 + n * 16 + lr) * 32 + aswz;

  f32x4 acc[4][4] = {};

  for (int kt = 0; kt < 32; ++kt) {
    gl16(pAh, dAh0);  gl16(pAh + 64 * EDIM, dAh1);
    gl16(pAl, dAl0);  gl16(pAl + 64 * EDIM, dAl1);
    gl16(pBh, dBh0);  gl16(pBh + 64 * EDIM, dBh1);
    gl16(pBl, dBl0);  gl16(pBl + 64 * EDIM, dBl1);
    pAh += 32; pAl += 32; pBh += 32; pBl += 32;

    __syncthreads();

    f16x8 ah[4], al[4], bh[4], bl[4];
#pragma unroll
    for (int m = 0; m < 4; m++) {
      ah[m] = *(const f16x8*)&lAh[aidx[m]];
      al[m] = *(const f16x8*)&lAl[aidx[m]];
    }
#pragma unroll
    for (int n = 0; n < 4; n++) {
      bh[n] = *(const f16x8*)&lBh[bidx[n]];
      bl[n] = *(const f16x8*)&lBl[bidx[n]];
    }
#pragma unroll
    for (int m = 0; m < 4; m++)
#pragma unroll
      for (int n = 0; n < 4; n++) {
        acc[m][n] = __builtin_amdgcn_mfma_f32_16x16x32_f16(ah[m], bh[n], acc[m][n], 0, 0, 0);
        acc[m][n] = __builtin_amdgcn_mfma_f32_16x16x32_f16(ah[m], bl[n], acc[m][n], 0, 0, 0);
        acc[m][n] = __builtin_amdgcn_mfma_f32_16x16x32_f16(al[m], bh[n], acc[m][n], 0, 0, 0);
      }

    __syncthreads();
  }

  int row0 = rowblk + wr * 64, col0 = colblk + wc * 64;
  float bv[4];
#pragma unroll
  for (int n = 0; n < 4; n++) bv[n] = bias[col0 + n * 16 + lr];
#pragma unroll
  for (int m = 0; m < 4; m++) {
    int r0 = row0 + m * 16 + lk * 4;
#pragma unroll
    for (int n = 0; n < 4; n++) {
      int c = col0 + n * 16 + lr;
      float* dst = outp + (size_t)r0 * EDIM + c;
#pragma unroll
      for (int i = 0; i < 4; i++)
        dst[(size_t)i * EDIM] = acc[m][n][i] + bv[n];
    }
  }
}

extern "C" void kernel_launch(void* const* d_in, const int* in_sizes, int n_in,
                              void* d_out, int out_size, void* d_ws, size_t ws_size,
                              hipStream_t stream) {
  const float* x  = (const float*)d_in[0];
  const float* wq = (const float*)d_in[1];
  const float* wk = (const float*)d_in[2];
  const float* wv = (const float*)d_in[3];
  const float* wo = (const float*)d_in[4];
  const float* qb = (const float*)d_in[5];
  const float* kb = (const float*)d_in[6];
  const float* vb = (const float*)d_in[7];
  const float* ob = (const float*)d_in[8];

  float* outp = (float*)d_out;
  float* attn = outp + (size_t)4 * 1024 * 1024;   // [64][1024][1024] fp32

  // workspace layout (306.2 MB)
  char* w = (char*)d_ws;
  f16* xhi = (f16*)w;  w += (size_t)33554432 * 2;
  f16* xlo = (f16*)w;  w += (size_t)33554432 * 2;
  f16* wqh = (f16*)w;  w += (size_t)8388608 * 2;
  f16* wql = (f16*)w;  w += (size_t)8388608 * 2;
  f16* wkh = (f16*)w;  w += (size_t)8388608 * 2;
  f16* wkl = (f16*)w;  w += (size_t)8388608 * 2;
  f16* wvh = (f16*)w;  w += (size_t)8388608 * 2;
  f16* wvl = (f16*)w;  w += (size_t)8388608 * 2;
  float* Q = (float*)w;   w += (size_t)4194304 * 4;
  float* K = (float*)w;   w += (size_t)4194304 * 4;
  float* V = (float*)w;   w += (size_t)4194304 * 4;
  f16* aoh = (f16*)w;     w += (size_t)4194304 * 2;
  f16* aol = (f16*)w;     w += (size_t)4194304 * 2;
  f16* wsth = (f16*)w;    w += (size_t)1048576 * 2;
  f16* wstl = (f16*)w;    w += (size_t)1048576 * 2;

  // 1. hi/lo splits
  k_split<<<8192, 256, 0, stream>>>(x, xhi, xlo, 4194304);
  k_split<<<4096, 256, 0, stream>>>(wq, wqh, wql, 1048576);
  k_split<<<4096, 256, 0, stream>>>(wk, wkh, wkl, 1048576);
  k_split<<<4096, 256, 0, stream>>>(wv, wvh, wvl, 1048576);
  // 2. transposed d-reduced output weight (f16 hi/lo)
  k_wsumt<<<dim3(32, 16), 256, 0, stream>>>(wo, wsth, wstl);
  // 3. QKV projections (row-block slowest for L3 residency)
  k_gemm_qkv<<<dim3(8, 3, 32), 256, 0, stream>>>(xhi, xlo, wqh, wql, wkh, wkl,
                                                 wvh, wvl, qb, kb, vb, Q, K, V);
  // 4. fused attention: scores + softmax + P-write + PV
  k_attn<<<dim3(16, 64), 256, 0, stream>>>(Q, K, V, attn, aoh, aol);
  // 5. output projection MFMA + bias
  k_outproj<<<dim3(8, 32), 256, 0, stream>>>(aoh, aol, wsth, wstl, ob, outp);
}